// Round 1
// baseline (278.537 us; speedup 1.0000x reference)
//
#include <hip/hip_runtime.h>
#include <float.h>
#include <stdint.h>

#define BB 4
#define NN 20000
#define MM 1024
#define CAP 256
#define KSEL 50

// order-preserving float -> uint32 map (total order incl. negatives)
__device__ __forceinline__ unsigned int fkey(float d) {
    unsigned int u = __float_as_uint(d);
    return (u & 0x80000000u) ? ~u : (u | 0x80000000u);
}
__device__ __forceinline__ unsigned long long umin64(unsigned long long a, unsigned long long b) {
    return a < b ? a : b;
}

// pack keypoints as float4 {x,y,z,|k|^2} for wave-uniform scalar loads
__global__ __launch_bounds__(256) void k_prep(const float* __restrict__ kp,
                                              float4* __restrict__ kp4) {
    int i = blockIdx.x * 256 + threadIdx.x;   // over BB*MM
    if (i >= BB * MM) return;
    float x = kp[i * 3 + 0], y = kp[i * 3 + 1], z = kp[i * 3 + 2];
    kp4[i] = make_float4(x, y, z, x * x + y * y + z * z);
}

__global__ __launch_bounds__(256) void k_assign(
    const float* __restrict__ pts, const float4* __restrict__ kp4,
    const float* __restrict__ pose,
    int* __restrict__ p2n, float* __restrict__ dsq,
    float* __restrict__ ptx, float* __restrict__ pty, float* __restrict__ ptz,
    int* __restrict__ cnt, int* __restrict__ lst)
{
    const int b = blockIdx.y;
    const int n = blockIdx.x * 256 + threadIdx.x;
    if (n >= NN) return;
    const float* p = pts + (b * NN + n) * 3;
    const float px = p[0], py = p[1], pz = p[2];
    const float psq = px * px + py * py + pz * pz;
    const float4* kq = kp4 + b * MM;
    float best = FLT_MAX; int bi = 0;
    #pragma unroll 4
    for (int j = 0; j < MM; ++j) {
        float4 q = kq[j];                      // uniform address -> s_load_dwordx4
        float dot = q.x * px + q.y * py + q.z * pz;
        float d = (q.w + psq) - 2.0f * dot;    // same formula as reference
        if (d < best) { best = d; bi = j; }    // strict < : first-min like jnp.argmin
    }
    const float* P = pose + b * 16;
    float tx = P[0] * px + P[1] * py + P[2]  * pz + P[3];
    float ty = P[4] * px + P[5] * py + P[6]  * pz + P[7];
    float tz = P[8] * px + P[9] * py + P[10] * pz + P[11];
    int g = b * NN + n;
    p2n[g] = bi; dsq[g] = best;
    ptx[g] = tx; pty[g] = ty; ptz[g] = tz;
    int node = b * MM + bi;
    int s = atomicAdd(&cnt[node], 1);
    if (s < CAP) lst[node * CAP + s] = n;      // set-deterministic, order-free
}

__global__ __launch_bounds__(256) void k_select(
    const int* __restrict__ p2n, const float* __restrict__ dsq,
    const float* __restrict__ ptx, const float* __restrict__ pty, const float* __restrict__ ptz,
    const int* __restrict__ cnt, const int* __restrict__ lst,
    const float* __restrict__ kpw, const float* __restrict__ ow,
    float* __restrict__ acc)
{
    const int node = blockIdx.x;          // b*MM + m
    const int b = node >> 10;
    const int m = node & (MM - 1);
    const int base = b * NN;
    const int c = cnt[node];
    const int tid = threadIdx.x;
    float sx = 0.f, sy = 0.f, sz = 0.f;

    if (c <= KSEL) {
        // all assigned selected + (50-c) lowest-index non-assigned fillers.
        // k-th needed filler index <= (k-1)+c <= 49, so candidates are n in [0,50).
        if (tid >= 64) return;
        if (tid < c) {
            int n = lst[node * CAP + tid];
            sx += ptx[base + n]; sy += pty[base + n]; sz += ptz[base + n];
        }
        int k = KSEL - c;
        bool flag = (tid < KSEL) && (p2n[base + tid] != m);
        unsigned long long mask = __ballot(flag);
        int rank = __popcll(mask & ((1ULL << tid) - 1ULL));
        if (flag && rank < k) {
            sx += ptx[base + tid]; sy += pty[base + tid]; sz += ptz[base + tid];
        }
        #pragma unroll
        for (int off = 32; off; off >>= 1) {
            sx += __shfl_down(sx, off);
            sy += __shfl_down(sy, off);
            sz += __shfl_down(sz, off);
        }
        if (tid == 0) {
            const float inv = 1.0f / (float)KSEL;
            float ex = sx * inv - kpw[node * 3 + 0];
            float ey = sy * inv - kpw[node * 3 + 1];
            float ez = sz * inv - kpw[node * 3 + 2];
            float corr = fabsf(ex) + fabsf(ey) + fabsf(ez);
            float w = ow[node];
            atomicAdd(&acc[0], w * corr);
            atomicAdd(&acc[1], w);
        }
        return;
    }

    // c > 50: extract the 50 smallest (dist, idx) among assigned points.
    // Packed key = (fkey(dist)<<32)|idx; extraction order strictly increasing,
    // so filter "key > last" replaces per-entry invalidation.
    __shared__ unsigned long long wmins[4];
    __shared__ unsigned long long winner_s;
    unsigned long long mykey = ~0ULL;
    const bool inlist = (c <= CAP);
    if (inlist && tid < c) {
        int n = lst[node * CAP + tid];
        mykey = ((unsigned long long)fkey(dsq[base + n]) << 32) | (unsigned int)n;
    }
    unsigned long long last = 0ULL;
    const int lane = tid & 63, wid = tid >> 6;
    for (int r = 0; r < KSEL; ++r) {
        unsigned long long cand;
        if (inlist) {
            cand = (mykey > last) ? mykey : ~0ULL;
        } else {
            cand = ~0ULL;   // rare overflow fallback: rescan all points
            for (int n = tid; n < NN; n += 256) {
                if (p2n[base + n] == m) {
                    unsigned long long key =
                        ((unsigned long long)fkey(dsq[base + n]) << 32) | (unsigned int)n;
                    if (key > last && key < cand) cand = key;
                }
            }
        }
        #pragma unroll
        for (int off = 32; off; off >>= 1)
            cand = umin64(cand, __shfl_xor(cand, off));
        if (lane == 0) wmins[wid] = cand;
        __syncthreads();
        if (tid == 0) {
            unsigned long long w = umin64(umin64(wmins[0], wmins[1]),
                                          umin64(wmins[2], wmins[3]));
            winner_s = w;
            int idx = (int)(unsigned int)(w & 0xFFFFFFFFULL);
            sx += ptx[base + idx]; sy += pty[base + idx]; sz += ptz[base + idx];
        }
        __syncthreads();
        last = winner_s;
    }
    if (tid == 0) {
        const float inv = 1.0f / (float)KSEL;
        float ex = sx * inv - kpw[node * 3 + 0];
        float ey = sy * inv - kpw[node * 3 + 1];
        float ez = sz * inv - kpw[node * 3 + 2];
        float corr = fabsf(ex) + fabsf(ey) + fabsf(ez);
        float w = ow[node];
        atomicAdd(&acc[0], w * corr);
        atomicAdd(&acc[1], w);
    }
}

__global__ void k_final(const float* __restrict__ acc, float* __restrict__ out) {
    out[0] = acc[0] / fmaxf(acc[1], 1e-6f);
}

extern "C" void kernel_launch(void* const* d_in, const int* in_sizes, int n_in,
                              void* d_out, int out_size, void* d_ws, size_t ws_size,
                              hipStream_t stream) {
    const float* pts  = (const float*)d_in[0];  // B,N,3
    const float* kp   = (const float*)d_in[1];  // B,M,3
    const float* kpw  = (const float*)d_in[2];  // B,M,3
    const float* pose = (const float*)d_in[3];  // B,4,4
    const float* ow   = (const float*)d_in[4];  // B,M
    float* out = (float*)d_out;

    char* ws = (char*)d_ws;
    size_t off = 0;
    float* acc = (float*)(ws + off); off += 16;                       // 2 floats
    int*   cnt = (int*)(ws + off);   off += (size_t)BB * MM * 4;      // 16 KB
    float4* kp4 = (float4*)(ws + off); off += (size_t)BB * MM * 16;   // 64 KB
    int*   p2n = (int*)(ws + off);   off += (size_t)BB * NN * 4;
    float* dsq = (float*)(ws + off); off += (size_t)BB * NN * 4;
    float* ptx = (float*)(ws + off); off += (size_t)BB * NN * 4;
    float* pty = (float*)(ws + off); off += (size_t)BB * NN * 4;
    float* ptz = (float*)(ws + off); off += (size_t)BB * NN * 4;
    int*   lst = (int*)(ws + off);   off += (size_t)BB * MM * CAP * 4; // 4 MB

    // zero acc + cnt (d_ws is re-poisoned to 0xAA before every launch)
    hipMemsetAsync(d_ws, 0, 16 + (size_t)BB * MM * 4, stream);

    k_prep<<<(BB * MM + 255) / 256, 256, 0, stream>>>(kp, kp4);
    dim3 g1((NN + 255) / 256, BB);
    k_assign<<<g1, 256, 0, stream>>>(pts, kp4, pose, p2n, dsq, ptx, pty, ptz, cnt, lst);
    k_select<<<BB * MM, 256, 0, stream>>>(p2n, dsq, ptx, pty, ptz, cnt, lst, kpw, ow, acc);
    k_final<<<1, 1, 0, stream>>>(acc, out);
}